// Round 7
// baseline (114.848 us; speedup 1.0000x reference)
//
#include <hip/hip_runtime.h>

// Depthwise 4x4 FIR blur, pad (2,2)/(2,2), NCHW fp32.
// x: [16,256,128,128] -> out: [16,256,129,129]
//
// Block = half image (64 output rows; s==1 also row 128), 512 threads.
// Stage all 66 valid input rows (33 x 1KB global_load_lds pairs) + zero pad
// rows + a dedicated zero-row (slot 68), ONE __syncthreads, then compute.
// LDS slot k = input row 64s-2+k. Thread = 4 output cols (g=tid&31) x 4 rows
// (c=tid>>5); both window reads are unconditional ds_read_b128 (g==0's left
// read is redirected to the zero-row via cndmask). Edge cols 126..128 are a
// once-per-block 65-thread mini-phase (no per-CS broadcast waste).
// XCD-swizzled blockIdx: XCD x gets contiguous images, image halves co-XCD.

__global__ __launch_bounds__(512) void blur_half2(
    const float* __restrict__ x,
    const float* __restrict__ kern,
    float* __restrict__ out)
{
    __shared__ __align__(16) float lds[69 * 128];   // 68 row slots + zero-row

    const int tid  = threadIdx.x;
    const int bid  = blockIdx.x;
    // bijective XCD swizzle: 8192 blocks = 8 XCDs x 1024
    const int wk   = ((bid & 7) << 10) | (bid >> 3);
    const int img  = wk >> 1;
    const int s    = wk & 1;         // half: out rows [64s, 64s+64)
    const int wv   = tid >> 6;
    const int lane = tid & 63;

    const float* __restrict__ xi = x + (size_t)img * (128 * 128);
    float* __restrict__ oi = out + (size_t)img * (129 * 129);

    // ---- stage: pair p = LDS slots (2p, 2p+1) = input rows 64s-2+2p, +1.
    // Valid pairs: s==0 -> p=1..33 (rows 0..65); s==1 -> p=0..32 (rows 62..127).
    const int P0 = s ? 0 : 1;
    const int P1 = s ? 32 : 33;
    for (int p = P0 + wv; p <= P1; p += 8) {
        const int row = 64 * s - 2 + 2 * p;
        const float* src = xi + (size_t)row * 128 + (lane << 2);
        const float* dst = &lds[p * 256];
        __builtin_amdgcn_global_load_lds(
            (const __attribute__((address_space(1))) unsigned int*)src,
            (__attribute__((address_space(3))) unsigned int*)dst, 16, 0, 0);
    }
    // zero pad rows + zero-row (disjoint from staged slots)
    if (tid < 256) {
        if (s) lds[8448 + tid] = 0.0f;   // slots 66,67 (rows 128,129)
        else   lds[tid]        = 0.0f;   // slots 0,1   (rows -2,-1)
    } else if (tid < 384) {
        lds[8448 + tid] = 0.0f;          // 8704..8831 = slot 68 (zero-row)
    }

    // 4x4 weights; uniform -> SGPRs
    float w[4][4];
#pragma unroll
    for (int p = 0; p < 4; ++p)
#pragma unroll
        for (int q = 0; q < 4; ++q)
            w[p][q] = kern[4 * p + q];

    __syncthreads();

    // ---- compute ----
    const int c  = tid >> 5;         // row subchunk 0..15 (4 rows each)
    const int g  = tid & 31;         // col group: out cols 4g-2 .. 4g+1
    const bool lv = (g >= 1);
    const float* const zrow = &lds[68 * 128];

    float xv[4][8];

    // out row i = 64s+4c+j window = slots 4c+j .. 4c+j+3; a = cols 4g-4..4g-1
    // (zero-row for g==0), b = cols 4g..4g+3. Both reads unconditional.
#define LLOAD(S, KK) do {                                                    \
        const float* pb_ = &lds[(4 * c + (KK)) * 128 + 4 * g];               \
        const float* pa_ = lv ? (pb_ - 4) : zrow;                            \
        float4 a_ = *(const float4*)pa_;                                     \
        float4 b_ = *(const float4*)pb_;                                     \
        xv[S][0] = a_.x; xv[S][1] = a_.y; xv[S][2] = a_.z; xv[S][3] = a_.w;  \
        xv[S][4] = b_.x; xv[S][5] = b_.y; xv[S][6] = b_.z; xv[S][7] = b_.w;  \
    } while (0)

#define ACCP(S, P) do {                                                      \
        o0 = fmaf(xv[S][0], w[P][0], o0);                                    \
        o1 = fmaf(xv[S][1], w[P][0], o1);                                    \
        o2 = fmaf(xv[S][2], w[P][0], o2);                                    \
        o3 = fmaf(xv[S][3], w[P][0], o3);                                    \
        o0 = fmaf(xv[S][1], w[P][1], o0);                                    \
        o1 = fmaf(xv[S][2], w[P][1], o1);                                    \
        o2 = fmaf(xv[S][3], w[P][1], o2);                                    \
        o3 = fmaf(xv[S][4], w[P][1], o3);                                    \
        o0 = fmaf(xv[S][2], w[P][2], o0);                                    \
        o1 = fmaf(xv[S][3], w[P][2], o1);                                    \
        o2 = fmaf(xv[S][4], w[P][2], o2);                                    \
        o3 = fmaf(xv[S][5], w[P][2], o3);                                    \
        o0 = fmaf(xv[S][3], w[P][3], o0);                                    \
        o1 = fmaf(xv[S][4], w[P][3], o1);                                    \
        o2 = fmaf(xv[S][5], w[P][3], o2);                                    \
        o3 = fmaf(xv[S][6], w[P][3], o3);                                    \
    } while (0)

#define CS(SA, SB, SC, SD, PO) do {                                          \
        float o0 = 0.f, o1 = 0.f, o2 = 0.f, o3 = 0.f;                        \
        ACCP(SA, 0); ACCP(SB, 1); ACCP(SC, 2); ACCP(SD, 3);                  \
        if (lv) { (PO)[0] = o0; (PO)[1] = o1; }                              \
        (PO)[2] = o2;                                                        \
        (PO)[3] = o3;                                                        \
    } while (0)

    {
        float* po = oi + (size_t)(64 * s + 4 * c) * 129 + 4 * g - 2;
        LLOAD(0, 0); LLOAD(1, 1); LLOAD(2, 2); LLOAD(3, 3);
        CS(0, 1, 2, 3, po); LLOAD(0, 4); po += 129;
        CS(1, 2, 3, 0, po); LLOAD(1, 5); po += 129;
        CS(2, 3, 0, 1, po); LLOAD(2, 6); po += 129;
        CS(3, 0, 1, 2, po); po += 129;
        if (s == 1 && c == 15) {                 // out row 128: slots 64..67
            LLOAD(3, 7);
            CS(0, 1, 2, 3, po);
        }
    }

    // ---- edge cols 126..128, once per block ----
    // out row 64s+tid (tid<64; s==1 also tid==64 -> row 128). Window =
    // slots tid..tid+3, floats 124..127 (cols 124..127); cols 128,129 pad.
    if (tid < (unsigned)(64 + s)) {
        float e0 = 0.f, e1 = 0.f, e2 = 0.f;
#pragma unroll
        for (int p = 0; p < 4; ++p) {
            float4 v = *(const float4*)&lds[(tid + p) * 128 + 124];
            e0 = fmaf(v.x, w[p][0], e0);
            e0 = fmaf(v.y, w[p][1], e0);
            e0 = fmaf(v.z, w[p][2], e0);
            e0 = fmaf(v.w, w[p][3], e0);
            e1 = fmaf(v.y, w[p][0], e1);
            e1 = fmaf(v.z, w[p][1], e1);
            e1 = fmaf(v.w, w[p][2], e1);
            e2 = fmaf(v.z, w[p][0], e2);
            e2 = fmaf(v.w, w[p][1], e2);
        }
        float* po = oi + (size_t)(64 * s + tid) * 129 + 126;
        po[0] = e0; po[1] = e1; po[2] = e2;
    }

#undef LLOAD
#undef ACCP
#undef CS
}

extern "C" void kernel_launch(void* const* d_in, const int* in_sizes, int n_in,
                              void* d_out, int out_size, void* d_ws, size_t ws_size,
                              hipStream_t stream) {
    const float* x    = (const float*)d_in[0];
    const float* kern = (const float*)d_in[1];
    float* out        = (float*)d_out;

    // 4096 images * 2 halves = 8192 blocks
    dim3 grid(8192), block(512);
    hipLaunchKernelGGL(blur_half2, grid, block, 0, stream, x, kern, out);
}

// Round 8
// 109.667 us; speedup vs baseline: 1.0472x; 1.0472x over previous
//
#include <hip/hip_runtime.h>

// Depthwise 4x4 FIR blur, pad (2,2)/(2,2), NCHW fp32.
// x: [16,256,128,128] -> out: [16,256,129,129]
//
// Block = half image (64 output rows; s==1 also row 128), 512 threads.
// Stage all 66 valid input rows (33 x 1KB global_load_lds pairs) + zero pad
// rows + zero-row, ONE __syncthreads, then compute. Thread = 4 output cols
// (g=tid&31) x 4 rows (c=tid>>5) via ds_read_b128 register ring.
// NEW: dense store path. Per CS step each half-wave holds one full row ->
// bounce through a wave-local LDS row buffer (ds_write_b128, +2-col pad for
// alignment; lane 31 adds edge cols 126..128), wave-local lgkmcnt(0), then
// flush as dense per-lane dword stores (32 contiguous dwords/inst) instead
// of 16B-strided dwords (4x fewer L2 line-transactions on the write path).

__global__ __launch_bounds__(512) void blur_half3(
    const float* __restrict__ x,
    const float* __restrict__ kern,
    float* __restrict__ out)
{
    // input rows: slots 0..67 (+ zero-row slot 68) = 8832 floats;
    // out bounce: 8 waves x 2 halves x 132 floats = 2112 floats. 43.8 KB.
    __shared__ __align__(16) float lds[69 * 128 + 8 * 264];

    const int tid  = threadIdx.x;
    const int bid  = blockIdx.x;
    // bijective XCD swizzle: 8192 blocks = 8 XCDs x 1024
    const int wk   = ((bid & 7) << 10) | (bid >> 3);
    const int img  = wk >> 1;
    const int s    = wk & 1;         // half: out rows [64s, 64s+64)
    const int wv   = tid >> 6;
    const int lane = tid & 63;

    const float* __restrict__ xi = x + (size_t)img * (128 * 128);
    float* __restrict__ oi = out + (size_t)img * (129 * 129);

    // ---- stage: pair p = LDS slots (2p, 2p+1) = input rows 64s-2+2p, +1.
    // Valid pairs: s==0 -> p=1..33 (rows 0..65); s==1 -> p=0..32 (rows 62..127).
    const int P0 = s ? 0 : 1;
    const int P1 = s ? 32 : 33;
    for (int p = P0 + wv; p <= P1; p += 8) {
        const int row = 64 * s - 2 + 2 * p;
        const float* src = xi + (size_t)row * 128 + (lane << 2);
        const float* dst = &lds[p * 256];
        __builtin_amdgcn_global_load_lds(
            (const __attribute__((address_space(1))) unsigned int*)src,
            (__attribute__((address_space(3))) unsigned int*)dst, 16, 0, 0);
    }
    // zero pad rows + zero-row (disjoint from staged slots)
    if (tid < 256) {
        if (s) lds[8448 + tid] = 0.0f;   // slots 66,67 (rows 128,129)
        else   lds[tid]        = 0.0f;   // slots 0,1   (rows -2,-1)
    } else if (tid < 384) {
        lds[8448 + tid] = 0.0f;          // 8704..8831 = slot 68 (zero-row)
    }

    // 4x4 weights; uniform -> SGPRs
    float w[4][4];
#pragma unroll
    for (int p = 0; p < 4; ++p)
#pragma unroll
        for (int q = 0; q < 4; ++q)
            w[p][q] = kern[4 * p + q];

    __syncthreads();

    // ---- compute ----
    const int c  = tid >> 5;         // row subchunk 0..15 (4 rows each)
    const int g  = tid & 31;         // col group: out cols 4g-2 .. 4g+1
    const bool lv = (g >= 1);
    const float* const zrow = &lds[68 * 128];
    // wave-local out bounce buffer: [wv][half][132]; col j at idx j+2
    float* const obuf = &lds[69 * 128 + wv * 264 + (c & 1) * 132];

    float xv[4][8];

    // out row i = 64s+4c+j window = slots 4c+j .. 4c+j+3; a = cols 4g-4..4g-1
    // (zero-row for g==0), b = cols 4g..4g+3. Both reads unconditional.
#define LLOAD(S, KK) do {                                                    \
        const float* pb_ = &lds[(4 * c + (KK)) * 128 + 4 * g];               \
        const float* pa_ = lv ? (pb_ - 4) : zrow;                            \
        float4 a_ = *(const float4*)pa_;                                     \
        float4 b_ = *(const float4*)pb_;                                     \
        xv[S][0] = a_.x; xv[S][1] = a_.y; xv[S][2] = a_.z; xv[S][3] = a_.w;  \
        xv[S][4] = b_.x; xv[S][5] = b_.y; xv[S][6] = b_.z; xv[S][7] = b_.w;  \
    } while (0)

#define ACCP(S, P) do {                                                      \
        o0 = fmaf(xv[S][0], w[P][0], o0);                                    \
        o1 = fmaf(xv[S][1], w[P][0], o1);                                    \
        o2 = fmaf(xv[S][2], w[P][0], o2);                                    \
        o3 = fmaf(xv[S][3], w[P][0], o3);                                    \
        o0 = fmaf(xv[S][1], w[P][1], o0);                                    \
        o1 = fmaf(xv[S][2], w[P][1], o1);                                    \
        o2 = fmaf(xv[S][3], w[P][1], o2);                                    \
        o3 = fmaf(xv[S][4], w[P][1], o3);                                    \
        o0 = fmaf(xv[S][2], w[P][2], o0);                                    \
        o1 = fmaf(xv[S][3], w[P][2], o1);                                    \
        o2 = fmaf(xv[S][4], w[P][2], o2);                                    \
        o3 = fmaf(xv[S][5], w[P][2], o3);                                    \
        o0 = fmaf(xv[S][3], w[P][3], o0);                                    \
        o1 = fmaf(xv[S][4], w[P][3], o1);                                    \
        o2 = fmaf(xv[S][5], w[P][3], o2);                                    \
        o3 = fmaf(xv[S][6], w[P][3], o3);                                    \
    } while (0)

    // edge cols 126..128 for g==31 (xv[.][4..7] = input cols 124..127)
#define XROW(S, P) do {                                                      \
        e0 = fmaf(xv[S][4], w[P][0], e0);                                    \
        e0 = fmaf(xv[S][5], w[P][1], e0);                                    \
        e0 = fmaf(xv[S][6], w[P][2], e0);                                    \
        e0 = fmaf(xv[S][7], w[P][3], e0);                                    \
        e1 = fmaf(xv[S][5], w[P][0], e1);                                    \
        e1 = fmaf(xv[S][6], w[P][1], e1);                                    \
        e1 = fmaf(xv[S][7], w[P][2], e1);                                    \
        e2 = fmaf(xv[S][6], w[P][0], e2);                                    \
        e2 = fmaf(xv[S][7], w[P][1], e2);                                    \
    } while (0)

    // CS: compute row 64s+4c+J, bounce to obuf, flush densely.
#define CS(SA, SB, SC, SD, J) do {                                           \
        float o0 = 0.f, o1 = 0.f, o2 = 0.f, o3 = 0.f;                        \
        ACCP(SA, 0); ACCP(SB, 1); ACCP(SC, 2); ACCP(SD, 3);                  \
        *(float4*)&obuf[4 * g] = make_float4(o0, o1, o2, o3);                \
        if (g == 31) {                                                       \
            float e0 = 0.f, e1 = 0.f, e2 = 0.f;                              \
            XROW(SA, 0); XROW(SB, 1); XROW(SC, 2); XROW(SD, 3);              \
            *(float2*)&obuf[128] = make_float2(e0, e1);  /* cols 126,127 */  \
            obuf[130] = e2;                              /* col  128     */  \
        }                                                                    \
        asm volatile("s_waitcnt lgkmcnt(0)" ::: "memory");                   \
        __builtin_amdgcn_sched_barrier(0);                                   \
        {                                                                    \
            float* po_ = oi + (size_t)(64 * s + 4 * c + (J)) * 129;          \
            _Pragma("unroll")                                                \
            for (int k_ = 0; k_ < 4; ++k_)                                   \
                po_[g + 32 * k_] = obuf[2 + g + 32 * k_];                    \
            if (g == 0) po_[128] = obuf[130];                                \
        }                                                                    \
    } while (0)

    {
        LLOAD(0, 0); LLOAD(1, 1); LLOAD(2, 2); LLOAD(3, 3);
        CS(0, 1, 2, 3, 0); LLOAD(0, 4);
        CS(1, 2, 3, 0, 1); LLOAD(1, 5);
        CS(2, 3, 0, 1, 2); LLOAD(2, 6);
        CS(3, 0, 1, 2, 3);
        if (s == 1 && c == 15) {                 // out row 128: slots 64..67
            LLOAD(3, 7);
            CS(0, 1, 2, 3, 4);
        }
    }

#undef LLOAD
#undef ACCP
#undef XROW
#undef CS
}

extern "C" void kernel_launch(void* const* d_in, const int* in_sizes, int n_in,
                              void* d_out, int out_size, void* d_ws, size_t ws_size,
                              hipStream_t stream) {
    const float* x    = (const float*)d_in[0];
    const float* kern = (const float*)d_in[1];
    float* out        = (float*)d_out;

    // 4096 images * 2 halves = 8192 blocks
    dim3 grid(8192), block(512);
    hipLaunchKernelGGL(blur_half3, grid, block, 0, stream, x, kern, out);
}